// Round 2
// baseline (5699.549 us; speedup 1.0000x reference)
//
#include <hip/hip_runtime.h>
#include <hip/hip_fp16.h>

// Problem constants (fixed by the reference)
#define U_N   100000
#define I_N   50000
#define NTOT  150000
#define DIM   64
#define NNZ   4800000
#define NM    (NTOT * DIM)          // 9,600,000 floats per output half

#define BROWS 64                                   // rows per bucket (2^6)
#define NBUCK ((NTOT + BROWS - 1) / BROWS)         // 2344
#define NSEG  (NBUCK * 8)                          // 18752 (8 XCD sub-cursors)

#define GRID_EDGES 2048                            // 2048 blocks x 256 thr; stride 524288
// g(i) = (i>>8)&7 == processing-block&7 for grid-stride with 2048x256

// ---------------------------------------------------------------------------
// 1) per-(bucket, xcd-group) histogram of edges
__global__ void count_kernel(const int* __restrict__ row, int* __restrict__ counts) {
    int i = blockIdx.x * blockDim.x + threadIdx.x;
    int stride = gridDim.x * blockDim.x;
    for (; i < NNZ; i += stride) {
        int r = row[i];
        int idx = ((r >> 6) << 3) | ((i >> 8) & 7);
        atomicAdd(&counts[idx], 1);
    }
}

// 2) single-block exclusive scan of 18752 counts -> sc (bases) and cur (cursors)
#define SCAN_THREADS 1024
#define SCAN_ITEMS   19            // 1024*19 = 19456 >= NSEG
__global__ void scan_kernel(const int* __restrict__ counts, int* __restrict__ sc,
                            int* __restrict__ cur) {
    __shared__ int sm[SCAN_THREADS];
    int t = threadIdx.x;
    int base = t * SCAN_ITEMS;
    int c[SCAN_ITEMS];
    int s = 0;
#pragma unroll
    for (int k = 0; k < SCAN_ITEMS; ++k) {
        int idx = base + k;
        c[k] = (idx < NSEG) ? counts[idx] : 0;
        s += c[k];
    }
    sm[t] = s; __syncthreads();
    int own = s;
    for (int off = 1; off < SCAN_THREADS; off <<= 1) {
        int add = (t >= off) ? sm[t - off] : 0;
        __syncthreads();
        sm[t] += add;
        __syncthreads();
    }
    int ex = sm[t] - own;
#pragma unroll
    for (int k = 0; k < SCAN_ITEMS; ++k) {
        int idx = base + k;
        if (idx < NSEG) { sc[idx] = ex; cur[idx] = ex; ex += c[k]; }
    }
    if (t == 0) sc[NSEG] = NNZ;
}

// 3) bin edges: bcv[pos] = (localrow<<24 | col, val). Append frontiers are
//    per-(bucket, blockIdx&7) so same-XCD blocks fill whole lines.
__global__ void bin_kernel(const int* __restrict__ row, const int* __restrict__ col,
                           const float* __restrict__ val, int* __restrict__ cur,
                           int2* __restrict__ bcv) {
    int i = blockIdx.x * blockDim.x + threadIdx.x;
    int stride = gridDim.x * blockDim.x;
    for (; i < NNZ; i += stride) {
        int r = row[i];
        int idx = ((r >> 6) << 3) | ((i >> 8) & 7);
        int pos = atomicAdd(&cur[idx], 1);
        bcv[pos] = make_int2(((r & 63) << 24) | col[i], __float_as_int(val[i]));
    }
}

// 4) out[0:NM] = emb0 (f32 concat); x0h = fp16 copy for gathering
__global__ void init_kernel(const float4* __restrict__ ue, const float4* __restrict__ ie,
                            float4* __restrict__ out, __half2* __restrict__ x0) {
    const int NM4 = NM / 4;
    const int U4  = U_N * DIM / 4;
    int i = blockIdx.x * blockDim.x + threadIdx.x;
    int stride = gridDim.x * blockDim.x;
    for (; i < NM4; i += stride) {
        float4 v = (i < U4) ? ue[i] : ie[i - U4];
        out[i] = v;
        x0[2 * i]     = __floats2half2_rn(v.x, v.y);
        x0[2 * i + 1] = __floats2half2_rn(v.z, v.w);
    }
}

// 5) SpMM: one block per 64-row bucket (dynamic ticket), LDS f32 accumulation.
//    MODE 0: y = acc (fp16).  MODE 1: out2 = 0.25*(e0 + y1 + y2 + acc) (f32).
template <int MODE>
__global__ __launch_bounds__(256, 8) void spmm_kernel(
        const int* __restrict__ sc, const int2* __restrict__ bcv,
        const __half* x, __half2* __restrict__ y,
        const float2* __restrict__ e0, const __half2* y1, const __half2* y2,
        float2* __restrict__ out2, int* __restrict__ ticket) {
    __shared__ float acc[BROWS * DIM];     // 16 KB
    __shared__ int sbuck;
    const int tid  = threadIdx.x;
    const int wid  = tid >> 6;
    const int lane = tid & 63;
    for (;;) {
        if (tid == 0) sbuck = atomicAdd(ticket, 1);
        __syncthreads();
        int b = sbuck;
        if (b >= NBUCK) return;            // uniform across block
#pragma unroll
        for (int k = tid; k < BROWS * DIM; k += 256) acc[k] = 0.f;
        __syncthreads();
        int s = sc[b << 3];
        int e = sc[(b + 1) << 3];
        int cnt  = e - s;
        int wlen = (cnt + 3) >> 2;
        int wbeg = s + wid * wlen;
        int wend = min(wbeg + wlen, e);
        int i = wbeg;
        for (; i + 4 <= wend; i += 4) {    // 4 independent gathers in flight
            int2 c0 = bcv[i], c1 = bcv[i + 1], c2 = bcv[i + 2], c3 = bcv[i + 3];
            float g0 = __half2float(x[((c0.x & 0xFFFFFF) << 6) + lane]);
            float g1 = __half2float(x[((c1.x & 0xFFFFFF) << 6) + lane]);
            float g2 = __half2float(x[((c2.x & 0xFFFFFF) << 6) + lane]);
            float g3 = __half2float(x[((c3.x & 0xFFFFFF) << 6) + lane]);
            atomicAdd(&acc[((c0.x >> 24) << 6) + lane], __int_as_float(c0.y) * g0);
            atomicAdd(&acc[((c1.x >> 24) << 6) + lane], __int_as_float(c1.y) * g1);
            atomicAdd(&acc[((c2.x >> 24) << 6) + lane], __int_as_float(c2.y) * g2);
            atomicAdd(&acc[((c3.x >> 24) << 6) + lane], __int_as_float(c3.y) * g3);
        }
        for (; i < wend; ++i) {
            int2 c = bcv[i];
            float g = __half2float(x[((c.x & 0xFFFFFF) << 6) + lane]);
            atomicAdd(&acc[((c.x >> 24) << 6) + lane], __int_as_float(c.y) * g);
        }
        __syncthreads();
        // epilogue: 64 rows x 64 dims, 2 elems per k (coalesced)
        int r0 = b << 6;
#pragma unroll
        for (int k = tid; k < BROWS * DIM / 2; k += 256) {
            int r = r0 + (k >> 5);
            if (r < NTOT) {
                float a0 = acc[(k << 1)];
                float a1 = acc[(k << 1) + 1];
                int gidx = (r0 << 5) + k;          // = r*32 + (k&31)
                if (MODE == 0) {
                    y[gidx] = __floats2half2_rn(a0, a1);
                } else {
                    float2 ev = e0[gidx];
                    float2 w1 = __half22float2(y1[gidx]);
                    float2 w2 = __half22float2(y2[gidx]);
                    float2 o;
                    o.x = 0.25f * (ev.x + w1.x + w2.x + a0);
                    o.y = 0.25f * (ev.y + w1.y + w2.y + a1);
                    out2[gidx] = o;
                }
            }
        }
        __syncthreads();                    // acc reads done before next zeroing
    }
}

// ---------------------------------------------------------------------------
extern "C" void kernel_launch(void* const* d_in, const int* in_sizes, int n_in,
                              void* d_out, int out_size, void* d_ws, size_t ws_size,
                              hipStream_t stream) {
    const float* ue  = (const float*)d_in[0];   // [100000,64]
    const float* ie  = (const float*)d_in[1];   // [50000,64]
    const float* val = (const float*)d_in[2];   // [4.8M]
    const int*   row = (const int*)d_in[3];     // [4.8M]
    const int*   col = (const int*)d_in[4];     // [4.8M]
    float* out = (float*)d_out;                 // [2*NM]: emb0 | light_out

    // workspace partition (~96.5 MB)
    char* ws = (char*)d_ws;
    size_t off = 0;
    auto alloc = [&](size_t bytes) -> void* {
        void* p = ws + off;
        off += (bytes + 511) & ~(size_t)511;
        return p;
    };
    int*     counts  = (int*)alloc(NSEG * sizeof(int));
    int*     sc      = (int*)alloc((NSEG + 1) * sizeof(int));
    int*     cur     = (int*)alloc(NSEG * sizeof(int));
    int*     tickets = (int*)alloc(4 * sizeof(int));
    int2*    bcv     = (int2*)alloc((size_t)NNZ * sizeof(int2));
    __half*  x0h     = (__half*)alloc((size_t)NM * sizeof(__half));
    __half*  y1h     = (__half*)alloc((size_t)NM * sizeof(__half));
    __half*  y2h     = (__half*)alloc((size_t)NM * sizeof(__half));
    (void)ws_size; (void)in_sizes; (void)n_in; (void)out_size;

    hipMemsetAsync(counts, 0, NSEG * sizeof(int), stream);
    hipMemsetAsync(tickets, 0, 4 * sizeof(int), stream);

    init_kernel<<<2048, 256, 0, stream>>>((const float4*)ue, (const float4*)ie,
                                          (float4*)out, (__half2*)x0h);
    count_kernel<<<GRID_EDGES, 256, 0, stream>>>(row, counts);
    scan_kernel<<<1, SCAN_THREADS, 0, stream>>>(counts, sc, cur);
    bin_kernel<<<GRID_EDGES, 256, 0, stream>>>(row, col, val, cur, bcv);

    float2* e0f2  = (float2*)out;
    float2* out2  = (float2*)(out + NM);
    // layer 1: gather emb0(fp16) -> y1
    spmm_kernel<0><<<2048, 256, 0, stream>>>(sc, bcv, x0h, (__half2*)y1h,
                                             nullptr, nullptr, nullptr, nullptr,
                                             tickets + 0);
    // layer 2: gather y1 -> y2
    spmm_kernel<0><<<2048, 256, 0, stream>>>(sc, bcv, y1h, (__half2*)y2h,
                                             nullptr, nullptr, nullptr, nullptr,
                                             tickets + 1);
    // layer 3: gather y2, fuse final combine out2 = 0.25*(e0+y1+y2+y3)
    spmm_kernel<1><<<2048, 256, 0, stream>>>(sc, bcv, y2h, nullptr,
                                             e0f2, (const __half2*)y1h,
                                             (const __half2*)y2h, out2,
                                             tickets + 2);
}

// Round 4
// 964.072 us; speedup vs baseline: 5.9120x; 5.9120x over previous
//
#include <hip/hip_runtime.h>
#include <hip/hip_fp16.h>

// Problem constants (fixed by the reference)
#define U_N   100000
#define I_N   50000
#define NTOT  150000
#define DIM   64
#define NNZ   4800000
#define NM    (NTOT * DIM)          // 9,600,000 floats per output half

#define BROWS 64                                   // rows per bucket
#define NBUCK ((NTOT + BROWS - 1) / BROWS)         // 2344
#define NSEG  (NBUCK * 8)                          // 18752 (8 XCD sub-frontiers)

#define GRID_EDGES 2048                            // grid-stride over edges

// ---------------------------------------------------------------------------
// 1) per-(bucket, xcd-group) histogram. Sub-frontier id (i>>8)&7 == block&7 ==
//    XCD id, so each frontier is later appended only from one XCD's L2.
__global__ void count_kernel(const int* __restrict__ row, int* __restrict__ counts) {
    int i = blockIdx.x * blockDim.x + threadIdx.x;
    int stride = gridDim.x * blockDim.x;
    for (; i < NNZ; i += stride) {
        int r = row[i];
        atomicAdd(&counts[((r >> 6) << 3) | ((i >> 8) & 7)], 1);
    }
}

// 2) single-block exclusive scan of NSEG counts -> sc (bases) and cur (cursors)
#define SCAN_THREADS 1024
#define SCAN_ITEMS   19            // 1024*19 = 19456 >= NSEG
__global__ void scan_kernel(const int* __restrict__ counts, int* __restrict__ sc,
                            int* __restrict__ cur) {
    __shared__ int sm[SCAN_THREADS];
    int t = threadIdx.x;
    int base = t * SCAN_ITEMS;
    int c[SCAN_ITEMS];
    int s = 0;
#pragma unroll
    for (int k = 0; k < SCAN_ITEMS; ++k) {
        int idx = base + k;
        c[k] = (idx < NSEG) ? counts[idx] : 0;
        s += c[k];
    }
    sm[t] = s; __syncthreads();
    int own = s;
    for (int off = 1; off < SCAN_THREADS; off <<= 1) {
        int add = (t >= off) ? sm[t - off] : 0;
        __syncthreads();
        sm[t] += add;
        __syncthreads();
    }
    int ex = sm[t] - own;
#pragma unroll
    for (int k = 0; k < SCAN_ITEMS; ++k) {
        int idx = base + k;
        if (idx < NSEG) { sc[idx] = ex; cur[idx] = ex; ex += c[k]; }
    }
    if (t == 0) sc[NSEG] = NNZ;
}

// 3) bin edges into bucket segments: bcv[pos] = (lrow<<24 | col, val)
__global__ void bin_kernel(const int* __restrict__ row, const int* __restrict__ col,
                           const float* __restrict__ val, int* __restrict__ cur,
                           int2* __restrict__ bcv) {
    int i = blockIdx.x * blockDim.x + threadIdx.x;
    int stride = gridDim.x * blockDim.x;
    for (; i < NNZ; i += stride) {
        int r = row[i];
        int idx = ((r >> 6) << 3) | ((i >> 8) & 7);
        int pos = atomicAdd(&cur[idx], 1);
        bcv[pos] = make_int2(((r & 63) << 24) | col[i], __float_as_int(val[i]));
    }
}

// 4) per-bucket LDS counting sort -> exact row-major CSR (ecv = col,val) + rowptr.
//    int LDS atomics are native ds_add (no CAS loop).
__global__ __launch_bounds__(256) void rowsort_kernel(const int* __restrict__ sc,
                                                      const int2* __restrict__ bcv,
                                                      int2* __restrict__ ecv,
                                                      int* __restrict__ rowptr) {
    __shared__ int cnt[BROWS];
    __shared__ int pos[BROWS];
    int b = blockIdx.x;
    int tid = threadIdx.x;
    int s0 = sc[b << 3];
    int e0 = sc[(b + 1) << 3];
    if (tid < BROWS) cnt[tid] = 0;
    __syncthreads();
    for (int i = s0 + tid; i < e0; i += 256) atomicAdd(&cnt[bcv[i].x >> 24], 1);
    __syncthreads();
    if (tid < BROWS) {              // wave 0: 64-lane exclusive prefix via shfl
        int v = cnt[tid];
        int p = v;
        for (int off = 1; off < 64; off <<= 1) {
            int t2 = __shfl_up(p, off);
            if (tid >= off) p += t2;
        }
        int base = s0 + p - v;      // exclusive
        pos[tid] = base;
        int gr = (b << 6) + tid;
        if (gr <= NTOT) rowptr[gr] = base;   // last bucket's first absent row == NNZ
    }
    __syncthreads();
    for (int i = s0 + tid; i < e0; i += 256) {
        int2 v = bcv[i];
        int p = atomicAdd(&pos[v.x >> 24], 1);
        ecv[p] = make_int2(v.x & 0xFFFFFF, v.y);
    }
}

// 5) out[0:NM] = emb0 (f32 concat); x0h = fp16 copy for gathering
__global__ void init_kernel(const float4* __restrict__ ue, const float4* __restrict__ ie,
                            float4* __restrict__ out, __half2* __restrict__ x0) {
    const int NM4 = NM / 4;
    const int U4  = U_N * DIM / 4;
    int i = blockIdx.x * blockDim.x + threadIdx.x;
    int stride = gridDim.x * blockDim.x;
    for (; i < NM4; i += stride) {
        float4 v = (i < U4) ? ue[i] : ie[i - U4];
        out[i] = v;
        x0[2 * i]     = __floats2half2_rn(v.x, v.y);
        x0[2 * i + 1] = __floats2half2_rn(v.z, v.w);
    }
}

// 6) SpMM: one wave per row, lane = dim, register f32 accumulation.
//    fp16 gathers (128B/edge), software-prefetched 8-deep unroll.
//    MODE 0: y = acc (fp16).  MODE 1: out2 = 0.25*(e0 + y1 + y2 + acc) (f32).
template <int MODE>
__global__ __launch_bounds__(256) void spmm_kernel(
        const int* __restrict__ rowptr, const int2* __restrict__ ecv,
        const __half* __restrict__ x, __half* __restrict__ y,
        const float* __restrict__ e0, const __half* __restrict__ y1,
        const __half* __restrict__ y2, float* __restrict__ out2) {
    int row = blockIdx.x * 4 + (threadIdx.x >> 6);
    if (row >= NTOT) return;
    int lane = threadIdx.x & 63;
    int s = __builtin_amdgcn_readfirstlane(rowptr[row]);
    int e = __builtin_amdgcn_readfirstlane(rowptr[row + 1]);
    float a = 0.f;
    int i = s;
    if (i + 8 <= e) {
        int2 c0 = ecv[i],     c1 = ecv[i + 1], c2 = ecv[i + 2], c3 = ecv[i + 3];
        int2 c4 = ecv[i + 4], c5 = ecv[i + 5], c6 = ecv[i + 6], c7 = ecv[i + 7];
        for (; i + 16 <= e; i += 8) {
            // prefetch next cv batch BEFORE this batch's gathers enter the queue
            int2 n0 = ecv[i + 8],  n1 = ecv[i + 9],  n2 = ecv[i + 10], n3 = ecv[i + 11];
            int2 n4 = ecv[i + 12], n5 = ecv[i + 13], n6 = ecv[i + 14], n7 = ecv[i + 15];
            float g0 = __half2float(x[(c0.x << 6) + lane]);
            float g1 = __half2float(x[(c1.x << 6) + lane]);
            float g2 = __half2float(x[(c2.x << 6) + lane]);
            float g3 = __half2float(x[(c3.x << 6) + lane]);
            float g4 = __half2float(x[(c4.x << 6) + lane]);
            float g5 = __half2float(x[(c5.x << 6) + lane]);
            float g6 = __half2float(x[(c6.x << 6) + lane]);
            float g7 = __half2float(x[(c7.x << 6) + lane]);
            a = fmaf(__int_as_float(c0.y), g0, a);
            a = fmaf(__int_as_float(c1.y), g1, a);
            a = fmaf(__int_as_float(c2.y), g2, a);
            a = fmaf(__int_as_float(c3.y), g3, a);
            a = fmaf(__int_as_float(c4.y), g4, a);
            a = fmaf(__int_as_float(c5.y), g5, a);
            a = fmaf(__int_as_float(c6.y), g6, a);
            a = fmaf(__int_as_float(c7.y), g7, a);
            c0 = n0; c1 = n1; c2 = n2; c3 = n3;
            c4 = n4; c5 = n5; c6 = n6; c7 = n7;
        }
        a = fmaf(__int_as_float(c0.y), __half2float(x[(c0.x << 6) + lane]), a);
        a = fmaf(__int_as_float(c1.y), __half2float(x[(c1.x << 6) + lane]), a);
        a = fmaf(__int_as_float(c2.y), __half2float(x[(c2.x << 6) + lane]), a);
        a = fmaf(__int_as_float(c3.y), __half2float(x[(c3.x << 6) + lane]), a);
        a = fmaf(__int_as_float(c4.y), __half2float(x[(c4.x << 6) + lane]), a);
        a = fmaf(__int_as_float(c5.y), __half2float(x[(c5.x << 6) + lane]), a);
        a = fmaf(__int_as_float(c6.y), __half2float(x[(c6.x << 6) + lane]), a);
        a = fmaf(__int_as_float(c7.y), __half2float(x[(c7.x << 6) + lane]), a);
        i += 8;
    }
    for (; i < e; ++i) {
        int2 cv = ecv[i];
        a = fmaf(__int_as_float(cv.y), __half2float(x[(cv.x << 6) + lane]), a);
    }
    int o = (row << 6) + lane;
    if (MODE == 0) {
        y[o] = __float2half(a);
    } else {
        out2[o] = 0.25f * (e0[o] + __half2float(y1[o]) + __half2float(y2[o]) + a);
    }
}

// ---------------------------------------------------------------------------
extern "C" void kernel_launch(void* const* d_in, const int* in_sizes, int n_in,
                              void* d_out, int out_size, void* d_ws, size_t ws_size,
                              hipStream_t stream) {
    const float* ue  = (const float*)d_in[0];   // [100000,64]
    const float* ie  = (const float*)d_in[1];   // [50000,64]
    const float* val = (const float*)d_in[2];   // [4.8M]
    const int*   row = (const int*)d_in[3];     // [4.8M]
    const int*   col = (const int*)d_in[4];     // [4.8M]
    float* out = (float*)d_out;                 // [2*NM]: emb0 | light_out

    // workspace partition (~97 MB; y1/y2 overlay the dead bcv region)
    char* ws = (char*)d_ws;
    size_t off = 0;
    auto alloc = [&](size_t bytes) -> void* {
        void* p = ws + off;
        off += (bytes + 511) & ~(size_t)511;
        return p;
    };
    int*    counts = (int*)alloc(NSEG * sizeof(int));
    int*    sc     = (int*)alloc((NSEG + 1) * sizeof(int));
    int*    cur    = (int*)alloc(NSEG * sizeof(int));
    int*    rowptr = (int*)alloc((NTOT + 1) * sizeof(int));
    char*   bcvreg = (char*)alloc((size_t)NNZ * sizeof(int2));   // 38.4 MB, reused
    int2*   ecv    = (int2*)alloc((size_t)NNZ * sizeof(int2));   // 38.4 MB
    __half* x0h    = (__half*)alloc((size_t)NM * sizeof(__half));
    (void)ws_size; (void)in_sizes; (void)n_in; (void)out_size;

    int2*   bcv = (int2*)bcvreg;                 // live: bin..rowsort
    __half* y1h = (__half*)bcvreg;               // live: after rowsort
    __half* y2h = (__half*)(bcvreg + (size_t)NM * sizeof(__half));

    hipMemsetAsync(counts, 0, NSEG * sizeof(int), stream);

    init_kernel<<<2048, 256, 0, stream>>>((const float4*)ue, (const float4*)ie,
                                          (float4*)out, (__half2*)x0h);
    count_kernel<<<GRID_EDGES, 256, 0, stream>>>(row, counts);
    scan_kernel<<<1, SCAN_THREADS, 0, stream>>>(counts, sc, cur);
    bin_kernel<<<GRID_EDGES, 256, 0, stream>>>(row, col, val, cur, bcv);
    rowsort_kernel<<<NBUCK, 256, 0, stream>>>(sc, bcv, ecv, rowptr);

    const int SPMM_GRID = (NTOT + 3) / 4;       // 4 rows (waves) per block
    // layer 1: gather emb0(fp16) -> y1 (overwrites bcv region: bcv is dead now)
    spmm_kernel<0><<<SPMM_GRID, 256, 0, stream>>>(rowptr, ecv, x0h, y1h,
                                                  nullptr, nullptr, nullptr, nullptr);
    // layer 2: gather y1 -> y2
    spmm_kernel<0><<<SPMM_GRID, 256, 0, stream>>>(rowptr, ecv, y1h, y2h,
                                                  nullptr, nullptr, nullptr, nullptr);
    // layer 3: gather y2, fused final combine out2 = 0.25*(e0+y1+y2+y3)
    spmm_kernel<1><<<SPMM_GRID, 256, 0, stream>>>(rowptr, ecv, y2h, nullptr,
                                                  out, y1h, y2h, out + NM);
}

// Round 5
// 616.105 us; speedup vs baseline: 9.2509x; 1.5648x over previous
//
#include <hip/hip_runtime.h>
#include <hip/hip_fp16.h>

// Problem constants (fixed by the reference)
#define U_N   100000
#define I_N   50000
#define NTOT  150000
#define DIM   64
#define NNZ   4800000
#define NM    (NTOT * DIM)          // 9,600,000 floats per output half

// coarse buckets of 512 rows for the tile-staged partition
#define CB_LOG 9
#define CB     512
#define NB2    ((NTOT + CB - 1) / CB)       // 293
#define TILE   4096
#define NT2    ((NNZ + TILE - 1) / TILE)    // 1172 tiles/blocks

// ---------------------------------------------------------------------------
// 1) per-bucket histogram (LDS-aggregated, then one global add per bucket)
__global__ void count2_kernel(const int* __restrict__ row, int* __restrict__ gcount) {
    __shared__ int h[NB2];
    int tid = threadIdx.x;
    for (int k = tid; k < NB2; k += 256) h[k] = 0;
    __syncthreads();
    int i = blockIdx.x * blockDim.x + tid;
    int stride = gridDim.x * blockDim.x;
    for (; i < NNZ; i += stride) atomicAdd(&h[row[i] >> CB_LOG], 1);
    __syncthreads();
    for (int k = tid; k < NB2; k += 256)
        if (h[k]) atomicAdd(&gcount[k], h[k]);
}

// 2) single-block exclusive scan of 293 counts -> sc2 (segment bases) + gcur
__global__ void scan2_kernel(const int* __restrict__ gcount, int* __restrict__ sc2,
                             int* __restrict__ gcur) {
    __shared__ int sm[512];
    int t = threadIdx.x;
    int v = (t < NB2) ? gcount[t] : 0;
    sm[t] = v; __syncthreads();
    for (int off = 1; off < 512; off <<= 1) {
        int add = (t >= off) ? sm[t - off] : 0;
        __syncthreads();
        sm[t] += add;
        __syncthreads();
    }
    int ex = sm[t] - v;
    if (t < NB2) { sc2[t] = ex; gcur[t] = ex; }
    if (t == 0) sc2[NB2] = NNZ;
}

// 3) tile-staged partition: each block reorders a 4096-edge tile in LDS, then
//    writes one contiguous run per touched bucket (single atomic reserve per
//    run) -> mostly full-line HBM writes instead of random 8B appends.
//    bcv entry: ( (r&511)<<18 | col , val )   [col < 2^18, lrow 9 bits]
__global__ __launch_bounds__(256) void bin2_kernel(
        const int* __restrict__ row, const int* __restrict__ col,
        const float* __restrict__ val, int* __restrict__ gcur,
        int2* __restrict__ bcv) {
    __shared__ int  hist[NB2];
    __shared__ int  lofs[NB2];
    __shared__ int  gbase[NB2];
    __shared__ int2 stage[TILE];            // 32 KB
    __shared__ unsigned short sbuck[TILE];  // 8 KB
    const int tid  = threadIdx.x;
    const int base = blockIdx.x * TILE;
    const int n    = min(TILE, NNZ - base);

    for (int k = tid; k < NB2; k += 256) hist[k] = 0;
    __syncthreads();

    // load 16 edges/thread, histogram buckets
    int  erb[16]; int epk[16]; int evl[16];
#pragma unroll
    for (int k = 0; k < 16; ++k) {
        int i = base + k * 256 + tid;       // coalesced
        if (i < base + n) {
            int r = row[i];
            int b = r >> CB_LOG;
            erb[k] = b;
            epk[k] = ((r & (CB - 1)) << 18) | col[i];
            evl[k] = __float_as_int(val[i]);
            atomicAdd(&hist[b], 1);
        } else erb[k] = -1;
    }
    __syncthreads();

    // wave-0 exclusive scan of hist[293] -> lofs (5 shfl chunks with carry)
    if (tid < 64) {
        int carry = 0;
        for (int c = 0; c < 5; ++c) {
            int idx = c * 64 + tid;
            int v = (idx < NB2) ? hist[idx] : 0;
            int p = v;
            for (int off = 1; off < 64; off <<= 1) {
                int t2 = __shfl_up(p, off);
                if (tid >= off) p += t2;
            }
            if (idx < NB2) lofs[idx] = carry + p - v;
            carry += __shfl(p, 63);
        }
    }
    __syncthreads();

    // reorder tile into LDS (bucket-grouped)
#pragma unroll
    for (int k = 0; k < 16; ++k) {
        if (erb[k] >= 0) {
            int p = atomicAdd(&lofs[erb[k]], 1);
            stage[p] = make_int2(epk[k], evl[k]);
            sbuck[p] = (unsigned short)erb[k];
        }
    }
    __syncthreads();

    // reserve one contiguous run per touched bucket
    for (int b = tid; b < NB2; b += 256)
        if (hist[b]) gbase[b] = atomicAdd(&gcur[b], hist[b]);
    __syncthreads();

    // write out: consecutive threads -> consecutive positions within runs
    for (int j = tid; j < n; j += 256) {
        int b = sbuck[j];
        int lstart = lofs[b] - hist[b];     // lofs is now lend
        bcv[gbase[b] + (j - lstart)] = stage[j];
    }
}

// 4) per-bucket LDS counting sort (512 rows) -> exact row CSR (ecv) + rowptr
__global__ __launch_bounds__(256) void rowsort2_kernel(
        const int* __restrict__ sc2, const int2* __restrict__ bcv,
        int2* __restrict__ ecv, int* __restrict__ rowptr) {
    __shared__ int cnt[CB];
    __shared__ int ofs[CB];
    __shared__ int pos[CB];
    __shared__ int wsum[8];
    const int b   = blockIdx.x;
    const int tid = threadIdx.x;
    const int s0  = sc2[b];
    const int e0  = sc2[b + 1];
    for (int k = tid; k < CB; k += 256) cnt[k] = 0;
    __syncthreads();
    for (int i = s0 + tid; i < e0; i += 256) atomicAdd(&cnt[bcv[i].x >> 18], 1);
    __syncthreads();
    // scan 512 counters: 4 waves x 2 chunks of 64 via shfl, then combine
    {
        int lane = tid & 63, w = tid >> 6;
        for (int c = w; c < 8; c += 4) {
            int idx = c * 64 + lane;
            int v = cnt[idx];
            int p = v;
            for (int off = 1; off < 64; off <<= 1) {
                int t2 = __shfl_up(p, off);
                if (lane >= off) p += t2;
            }
            ofs[idx] = p - v;
            if (lane == 63) wsum[c] = p;
        }
    }
    __syncthreads();
    if (tid == 0) {
        int acc = 0;
        for (int c = 0; c < 8; ++c) { int t = wsum[c]; wsum[c] = acc; acc += t; }
    }
    __syncthreads();
    for (int idx = tid; idx < CB; idx += 256) {
        int basep = s0 + ofs[idx] + wsum[idx >> 6];
        pos[idx] = basep;
        int gr = (b << CB_LOG) + idx;
        if (gr <= NTOT) rowptr[gr] = basep;
    }
    __syncthreads();
    for (int i = s0 + tid; i < e0; i += 256) {
        int2 v = bcv[i];
        int p = atomicAdd(&pos[v.x >> 18], 1);
        ecv[p] = make_int2(v.x & 0x3FFFF, v.y);
    }
}

// 5) out[0:NM] = emb0 (f32 concat); x0h = fp16 copy for gathering
__global__ void init_kernel(const float4* __restrict__ ue, const float4* __restrict__ ie,
                            float4* __restrict__ out, __half2* __restrict__ x0) {
    const int NM4 = NM / 4;
    const int U4  = U_N * DIM / 4;
    int i = blockIdx.x * blockDim.x + threadIdx.x;
    int stride = gridDim.x * blockDim.x;
    for (; i < NM4; i += stride) {
        float4 v = (i < U4) ? ue[i] : ie[i - U4];
        out[i] = v;
        x0[2 * i]     = __floats2half2_rn(v.x, v.y);
        x0[2 * i + 1] = __floats2half2_rn(v.z, v.w);
    }
}

// 6) SpMM: one wave per row, lane = dim, register f32 accumulation.
//    fp16 gathers (128B/edge), software-prefetched 8-deep unroll.
//    MODE 0: y = acc (fp16).  MODE 1: out2 = 0.25*(e0 + y1 + y2 + acc) (f32).
template <int MODE>
__global__ __launch_bounds__(256) void spmm_kernel(
        const int* __restrict__ rowptr, const int2* __restrict__ ecv,
        const __half* __restrict__ x, __half* __restrict__ y,
        const float* __restrict__ e0, const __half* __restrict__ y1,
        const __half* __restrict__ y2, float* __restrict__ out2) {
    int row = blockIdx.x * 4 + (threadIdx.x >> 6);
    if (row >= NTOT) return;
    int lane = threadIdx.x & 63;
    int s = __builtin_amdgcn_readfirstlane(rowptr[row]);
    int e = __builtin_amdgcn_readfirstlane(rowptr[row + 1]);
    float a = 0.f;
    int i = s;
    if (i + 8 <= e) {
        int2 c0 = ecv[i],     c1 = ecv[i + 1], c2 = ecv[i + 2], c3 = ecv[i + 3];
        int2 c4 = ecv[i + 4], c5 = ecv[i + 5], c6 = ecv[i + 6], c7 = ecv[i + 7];
        for (; i + 16 <= e; i += 8) {
            int2 n0 = ecv[i + 8],  n1 = ecv[i + 9],  n2 = ecv[i + 10], n3 = ecv[i + 11];
            int2 n4 = ecv[i + 12], n5 = ecv[i + 13], n6 = ecv[i + 14], n7 = ecv[i + 15];
            float g0 = __half2float(x[(c0.x << 6) + lane]);
            float g1 = __half2float(x[(c1.x << 6) + lane]);
            float g2 = __half2float(x[(c2.x << 6) + lane]);
            float g3 = __half2float(x[(c3.x << 6) + lane]);
            float g4 = __half2float(x[(c4.x << 6) + lane]);
            float g5 = __half2float(x[(c5.x << 6) + lane]);
            float g6 = __half2float(x[(c6.x << 6) + lane]);
            float g7 = __half2float(x[(c7.x << 6) + lane]);
            a = fmaf(__int_as_float(c0.y), g0, a);
            a = fmaf(__int_as_float(c1.y), g1, a);
            a = fmaf(__int_as_float(c2.y), g2, a);
            a = fmaf(__int_as_float(c3.y), g3, a);
            a = fmaf(__int_as_float(c4.y), g4, a);
            a = fmaf(__int_as_float(c5.y), g5, a);
            a = fmaf(__int_as_float(c6.y), g6, a);
            a = fmaf(__int_as_float(c7.y), g7, a);
            c0 = n0; c1 = n1; c2 = n2; c3 = n3;
            c4 = n4; c5 = n5; c6 = n6; c7 = n7;
        }
        a = fmaf(__int_as_float(c0.y), __half2float(x[(c0.x << 6) + lane]), a);
        a = fmaf(__int_as_float(c1.y), __half2float(x[(c1.x << 6) + lane]), a);
        a = fmaf(__int_as_float(c2.y), __half2float(x[(c2.x << 6) + lane]), a);
        a = fmaf(__int_as_float(c3.y), __half2float(x[(c3.x << 6) + lane]), a);
        a = fmaf(__int_as_float(c4.y), __half2float(x[(c4.x << 6) + lane]), a);
        a = fmaf(__int_as_float(c5.y), __half2float(x[(c5.x << 6) + lane]), a);
        a = fmaf(__int_as_float(c6.y), __half2float(x[(c6.x << 6) + lane]), a);
        a = fmaf(__int_as_float(c7.y), __half2float(x[(c7.x << 6) + lane]), a);
        i += 8;
    }
    for (; i < e; ++i) {
        int2 cv = ecv[i];
        a = fmaf(__int_as_float(cv.y), __half2float(x[(cv.x << 6) + lane]), a);
    }
    int o = (row << 6) + lane;
    if (MODE == 0) {
        y[o] = __float2half(a);
    } else {
        out2[o] = 0.25f * (e0[o] + __half2float(y1[o]) + __half2float(y2[o]) + a);
    }
}

// ---------------------------------------------------------------------------
extern "C" void kernel_launch(void* const* d_in, const int* in_sizes, int n_in,
                              void* d_out, int out_size, void* d_ws, size_t ws_size,
                              hipStream_t stream) {
    const float* ue  = (const float*)d_in[0];   // [100000,64]
    const float* ie  = (const float*)d_in[1];   // [50000,64]
    const float* val = (const float*)d_in[2];   // [4.8M]
    const int*   row = (const int*)d_in[3];     // [4.8M]
    const int*   col = (const int*)d_in[4];     // [4.8M]
    float* out = (float*)d_out;                 // [2*NM]: emb0 | light_out

    // workspace partition (~97 MB; y1/y2 overlay the dead bcv region)
    char* ws = (char*)d_ws;
    size_t off = 0;
    auto alloc = [&](size_t bytes) -> void* {
        void* p = ws + off;
        off += (bytes + 511) & ~(size_t)511;
        return p;
    };
    int*    gcount = (int*)alloc(NB2 * sizeof(int));
    int*    sc2    = (int*)alloc((NB2 + 1) * sizeof(int));
    int*    gcur   = (int*)alloc(NB2 * sizeof(int));
    int*    rowptr = (int*)alloc((NTOT + 1) * sizeof(int));
    char*   bcvreg = (char*)alloc((size_t)NNZ * sizeof(int2));   // 38.4 MB, reused
    int2*   ecv    = (int2*)alloc((size_t)NNZ * sizeof(int2));   // 38.4 MB
    __half* x0h    = (__half*)alloc((size_t)NM * sizeof(__half));
    (void)ws_size; (void)in_sizes; (void)n_in; (void)out_size;

    int2*   bcv = (int2*)bcvreg;                 // live: bin2..rowsort2
    __half* y1h = (__half*)bcvreg;               // live: after rowsort2
    __half* y2h = (__half*)(bcvreg + (size_t)NM * sizeof(__half));

    hipMemsetAsync(gcount, 0, NB2 * sizeof(int), stream);

    init_kernel<<<2048, 256, 0, stream>>>((const float4*)ue, (const float4*)ie,
                                          (float4*)out, (__half2*)x0h);
    count2_kernel<<<2048, 256, 0, stream>>>(row, gcount);
    scan2_kernel<<<1, 512, 0, stream>>>(gcount, sc2, gcur);
    bin2_kernel<<<NT2, 256, 0, stream>>>(row, col, val, gcur, bcv);
    rowsort2_kernel<<<NB2, 256, 0, stream>>>(sc2, bcv, ecv, rowptr);

    const int SPMM_GRID = (NTOT + 3) / 4;       // 4 rows (waves) per block
    // layer 1: gather emb0(fp16) -> y1 (overwrites bcv region: bcv is dead now)
    spmm_kernel<0><<<SPMM_GRID, 256, 0, stream>>>(rowptr, ecv, x0h, y1h,
                                                  nullptr, nullptr, nullptr, nullptr);
    // layer 2: gather y1 -> y2
    spmm_kernel<0><<<SPMM_GRID, 256, 0, stream>>>(rowptr, ecv, y1h, y2h,
                                                  nullptr, nullptr, nullptr, nullptr);
    // layer 3: gather y2, fused final combine out2 = 0.25*(e0+y1+y2+y3)
    spmm_kernel<1><<<SPMM_GRID, 256, 0, stream>>>(rowptr, ecv, y2h, nullptr,
                                                  out, y1h, y2h, out + NM);
}